// Round 4
// baseline (212.179 us; speedup 1.0000x reference)
//
#include <hip/hip_runtime.h>

#define C_IN   672
#define C_OUT  128
#define HW     49
#define XELEMS (C_IN*HW)      // 32928
#define BK     96             // K-chunk (3 MFMA k-steps)
#define NCH    7              // 672/96
#define CHUNK  (BK*HW)        // 4704 floats per chunk
#define RS     100            // hT row stride in halfs (200 B): MFMA-read ~2-way (free), write ~4-way (~free)
#define NROWS  64             // padded N (s) dimension
#define SSPAD  680            // s_ss entries: 672 + pad for speculative c0+1 read

typedef short  short8  __attribute__((ext_vector_type(8)));
typedef short  short4v __attribute__((ext_vector_type(4)));
typedef float  f4      __attribute__((ext_vector_type(4)));
typedef float  f2      __attribute__((ext_vector_type(2)));

template<int N> struct IC { static constexpr int v = N; };

__device__ __forceinline__ void waitlgkm0() {
    asm volatile("s_waitcnt lgkmcnt(0)" ::: "memory");
}

__device__ __forceinline__ unsigned short f2bf(float f) {
    unsigned u = __float_as_uint(f);
    u += 0x7fffu + ((u >> 16) & 1u);
    return (unsigned short)(u >> 16);
}

__global__ __launch_bounds__(256) void prep_kernel(
        const float* __restrict__ gamma,
        const float* __restrict__ beta,
        const float* __restrict__ rmean,
        const float* __restrict__ rvar,
        const float* __restrict__ W,
        unsigned short* __restrict__ Wbf,
        float* __restrict__ scale,
        float* __restrict__ shift) {
    int i = blockIdx.x * 256 + threadIdx.x;
    if (i < C_IN) {
        float inv = rsqrtf(rvar[i] + 1e-5f);
        float sc  = gamma[i] * inv;
        scale[i] = sc;
        shift[i] = beta[i] - rmean[i] * sc;
    }
    if (i < C_OUT * C_IN) Wbf[i] = f2bf(W[i]);
}

// out_b(128x49) = W(128x672) @ relu(x_b*scale+shift)(672x49), one block per b.
// R9: 3-deep x prefetch. R8 (reg-staged, 2-deep) broke the 218-us plateau
// (-7) but its issue->consume lead was only ~1 step (~300-500cy) vs ~900cy
// HBM latency: every transform stalled on vmcnt, and identical barrier
// skeletons phase-lock co-resident blocks so they stall TOGETHER (convoy).
// Now: xrA/B/C rotate; chunk kc+4 is issued at step kc and consumed at step
// kc+3 -> lead = 3 full steps (~1200+cy) > HBM latency, so the convoy always
// has >=2 chunks of requests in flight and transforms find data landed.
// All buffer selection is compile-time (template steps, rule #20).
// __launch_bounds__(512,4) caps VGPR at 128 -> 2 blocks/CU, 2 clean rounds.
// Barriers remain raw s_barrier + lgkmcnt(0): vmem never drained at barriers.
__global__ __launch_bounds__(512, 4) void gemm_kernel(
        const float* __restrict__ x,
        const unsigned short* __restrict__ Wbf,
        const float* __restrict__ scale,
        const float* __restrict__ shift,
        float* __restrict__ out) {
    __shared__ f2 s_ss[SSPAD];                       // (scale,shift) interleaved
    __shared__ unsigned short hT[2][NROWS * RS];     // 2 x 12.8 KB double buffer

    const int tid  = threadIdx.x;
    const int wv   = tid >> 6;          // 0..7, owns out rows wv*16..+15
    const int lane = tid & 63;
    const int quad = lane >> 4;
    const int l16  = lane & 15;
    const float* xb = x + (size_t)blockIdx.x * XELEMS;

    // zero both hT buffers once: pad rows 49..63 stay clean zeros
    for (int i = tid; i < (2 * NROWS * RS) / 4; i += 512)
        ((unsigned long long*)hT)[i] = 0ull;
    // stage interleaved (scale,shift); zero the speculative-read pad.
    // These loads precede all x issues, so their implicit vmcnt wait (before
    // the ds_write) never drains the x stream.
    for (int i = tid; i < C_IN; i += 512)
        s_ss[i] = (f2){scale[i], shift[i]};
    if (tid < SSPAD - C_IN) s_ss[C_IN + tid] = (f2){0.f, 0.f};

    // x chunk staging: 3 float4/thread (threads >=152 on r=2 clamp; their
    // stores are masked in transform). Per wave per r: 1 KB contiguous.
    f4 xrA[3], xrB[3], xrC[3];
    auto issue_x = [&](int kc, f4* xr) {
        const float* src = xb + kc * CHUNK;
        #pragma unroll
        for (int r = 0; r < 3; ++r) {
            int base = r * 2048 + tid * 4;
            if (base > CHUNK - 4) base = CHUNK - 4;
            xr[r] = *(const f4*)(src + base);
        }
    };

    short8 av[3];                       // current chunk's A-frags (L2-hot W)
    auto issue_av = [&](int kc) {
        int row = wv * 16 + l16;
        #pragma unroll
        for (int ks = 0; ks < 3; ++ks)
            av[ks] = *(const short8*)(Wbf + row * C_IN + kc * BK + ks * 32 + quad * 8);
    };

    // BN+ReLU+bf16 in register, scatter b16 into transposed hT[buf].
    auto transform = [&](int kc, const f4* xr, int buf) {
        unsigned short* h = &hT[buf][0];
        #pragma unroll
        for (int r = 0; r < 3; ++r) {
            int vb = r * 2048 + tid * 4;
            int cb = vb > CHUNK - 4 ? CHUNK - 4 : vb;   // matches issue_x clamp
            int c0 = cb / HW;                            // magic-div by 49
            int s0 = cb - c0 * HW;
            f2 p0 = s_ss[kc * BK + c0];
            f2 p1 = s_ss[kc * BK + c0 + 1];              // pad covers c0=95 edge
            #pragma unroll
            for (int jj = 0; jj < 4; ++jj) {
                int s = s0 + jj, c = c0;
                f2 pp = p0;
                if (s >= HW) { s -= HW; c = c0 + 1; pp = p1; }  // crosses <=1 boundary
                float v = fmaxf(xr[r][jj] * pp.x + pp.y, 0.f);
                if (r < 2 || vb + jj < CHUNK)            // r<2 folds to true
                    h[s * RS + c] = f2bf(v);
            }
        }
    };

    f4 acc[4];
    #pragma unroll
    for (int nt = 0; nt < 4; ++nt) acc[nt] = (f4){0.f, 0.f, 0.f, 0.f};

    auto mfma_phase = [&](int buf) {
        const unsigned short* h = &hT[buf][0];
        #pragma unroll
        for (int ks = 0; ks < 3; ++ks) {
            const int kloc = ks * 32 + quad * 8;
            short8 bv[4];
            #pragma unroll
            for (int nt = 0; nt < 4; ++nt) {
                int srow = nt * 16 + l16;                // ds_read_b64 pair, ~2-way banks
                const unsigned short* p = h + srow * RS + kloc;
                short4v lo = *(const short4v*)(p);
                short4v hi = *(const short4v*)(p + 4);
                bv[nt] = __builtin_shufflevector(lo, hi, 0, 1, 2, 3, 4, 5, 6, 7);
            }
            #pragma unroll
            for (int nt = 0; nt < 4; ++nt)
                acc[nt] = __builtin_amdgcn_mfma_f32_16x16x32_bf16(
                    av[ks], bv[nt], acc[nt], 0, 0, 0);
        }
    };

    // chunk kc lives in buffer kc%3 (all selections compile-time)
    auto xbuf_of = [&](auto kcc) -> f4* {
        constexpr int J = decltype(kcc)::v % 3;
        return J == 0 ? xrA : (J == 1 ? xrB : xrC);
    };

    // prologue: av(0) + x(0..2) in flight, then first transform + x(3)
    issue_av(0);
    issue_x(0, xrA); issue_x(1, xrB); issue_x(2, xrC);
    waitlgkm0();
    __builtin_amdgcn_s_barrier();       // hT zeros + s_ss visible; vmem stays in flight
    transform(0, xrA, 0);               // waits x(0) only (x1,x2,.. newer)
    issue_x(3, xrA);                    // xrA freed by transform(0)
    waitlgkm0();
    __builtin_amdgcn_s_barrier();       // hT[0] ready

    // step KC: MFMA(KC) from hT[KC&1] || transform(KC+1) -> hT[~] ||
    // issue x(KC+4) into the buffer transform(KC+1) just freed.
    // Passing barrier(KC) proves all waves finished MFMA(KC-1), so the
    // write of hT[(KC+1)&1] here is WAR-safe. One barrier per step.
    auto step = [&](auto kcc) {
        constexpr int KC = decltype(kcc)::v;
        mfma_phase(KC & 1);
        if constexpr (KC < NCH - 1) {
            issue_av(KC + 1);                            // av dead after mfma_phase
            transform(KC + 1, xbuf_of(IC<KC + 1>{}), (KC + 1) & 1);
            if constexpr (KC + 4 < NCH)
                issue_x(KC + 4, xbuf_of(IC<KC + 4>{}));  // 3-step lead
            waitlgkm0();
            __builtin_amdgcn_s_barrier();
        }
    };
    step(IC<0>{}); step(IC<1>{}); step(IC<2>{}); step(IC<3>{});
    step(IC<4>{}); step(IC<5>{}); step(IC<6>{});

    // epilogue: C/D layout col=lane&15, row=quad*4+reg (m89-verified); mask s>=49
    float* outb = out + (size_t)blockIdx.x * (C_OUT * HW);
    #pragma unroll
    for (int nt = 0; nt < 4; ++nt) {
        int scol = nt * 16 + l16;
        if (scol < HW) {
            #pragma unroll
            for (int i = 0; i < 4; ++i) {
                int o = wv * 16 + quad * 4 + i;
                outb[o * HW + scol] = acc[nt][i];
            }
        }
    }
}

extern "C" void kernel_launch(void* const* d_in, const int* in_sizes, int n_in,
                              void* d_out, int out_size, void* d_ws, size_t ws_size,
                              hipStream_t stream) {
    const float* x     = (const float*)d_in[0];
    const float* gamma = (const float*)d_in[1];
    const float* beta  = (const float*)d_in[2];
    const float* rmean = (const float*)d_in[3];
    const float* rvar  = (const float*)d_in[4];
    const float* W     = (const float*)d_in[5];
    float* out = (float*)d_out;

    // ws layout: [bf16 W: 86016*2 B][scale: 672 f32][shift: 672 f32]  (~173 KB)
    unsigned short* Wbf = (unsigned short*)d_ws;
    float* scale = (float*)((char*)d_ws + (size_t)C_OUT * C_IN * 2);
    float* shift = scale + C_IN;

    prep_kernel<<<(C_OUT * C_IN + 255) / 256, 256, 0, stream>>>(
        gamma, beta, rmean, rvar, W, Wbf, scale, shift);
    gemm_kernel<<<1024, 512, 0, stream>>>(x, Wbf, scale, shift, out);
}